// Round 1
// baseline (2546.877 us; speedup 1.0000x reference)
//
#include <hip/hip_runtime.h>

#define N_NODES 100000
#define N_EDGES 1000000
#define DIM 64
#define N_GRAPHS 1024
#define OUT_DIM 16
#define NLAYERS 4

#define BN 192      // nodes per block in layer kernel
#define NWAVES 3    // BN/64

// ---------------- CSR build ----------------
__global__ void count_kernel(const int* __restrict__ dst, int* __restrict__ counts) {
    int e = blockIdx.x * blockDim.x + threadIdx.x;
    if (e < N_EDGES) atomicAdd(&counts[dst[e]], 1);
}

__global__ __launch_bounds__(1024) void scan_kernel(int* __restrict__ row_ptr, int* __restrict__ cursor) {
    __shared__ int part[1024];
    const int T = 1024;
    const int C = (N_NODES + T - 1) / T;  // 98
    int t = threadIdx.x;
    int beg = t * C;
    int end = min(beg + C, N_NODES);
    int sum = 0;
    for (int i = beg; i < end; ++i) sum += row_ptr[i];
    part[t] = sum;
    __syncthreads();
    // Hillis-Steele inclusive scan over 1024 partials
    for (int off = 1; off < T; off <<= 1) {
        int v = (t >= off) ? part[t - off] : 0;
        __syncthreads();
        part[t] += v;
        __syncthreads();
    }
    int run = (t > 0) ? part[t - 1] : 0;  // exclusive prefix of this chunk
    for (int i = beg; i < end; ++i) {
        int c = row_ptr[i];
        row_ptr[i] = run;
        cursor[i] = run;
        run += c;
    }
    if (t == T - 1) row_ptr[N_NODES] = part[T - 1];
}

__global__ void scatter_kernel(const int* __restrict__ src, const int* __restrict__ dst,
                               int* __restrict__ cursor,
                               int* __restrict__ sorted_src, int* __restrict__ sorted_dst) {
    int e = blockIdx.x * blockDim.x + threadIdx.x;
    if (e < N_EDGES) {
        int d = dst[e];
        int pos = atomicAdd(&cursor[d], 1);
        sorted_src[pos] = src[e];
        sorted_dst[pos] = d;
    }
}

// ---------------- fused GraphConv layer ----------------
// Phase A: edge-parallel gather into LDS (rows padded to 65 -> 2-way bank alias, free)
// Phase B: thread-per-node register GEMM: out = agg@Wrel + brel + x@Wroot, relu
__global__ __launch_bounds__(BN) void layer_kernel(
    const float* __restrict__ hin, float* __restrict__ hout,
    const float* __restrict__ Wrel, const float* __restrict__ brel,
    const float* __restrict__ Wroot,
    const int* __restrict__ row_ptr,
    const int* __restrict__ sorted_src, const int* __restrict__ sorted_dst) {
    __shared__ float agg_s[BN * 65];
    const int tid = threadIdx.x;
    const int lane = tid & 63;
    const int wave = tid >> 6;
    const int node0 = blockIdx.x * BN;

    for (int i = tid; i < BN * 65; i += BN) agg_s[i] = 0.f;
    __syncthreads();

    const int nhi = min(node0 + BN, N_NODES);
    const int ebeg = row_ptr[node0];
    const int eend = row_ptr[nhi];
    const int total = eend - ebeg;
    const int chunk = (total + NWAVES - 1) / NWAVES;
    int wbeg = ebeg + wave * chunk;
    int wend = min(wbeg + chunk, eend);

    int e = wbeg;
    for (; e + 4 <= wend; e += 4) {
        // e is wave-uniform -> scalar loads for indices; row loads are coalesced 256B
        int s0 = sorted_src[e + 0], s1 = sorted_src[e + 1];
        int s2 = sorted_src[e + 2], s3 = sorted_src[e + 3];
        int d0 = sorted_dst[e + 0] - node0, d1 = sorted_dst[e + 1] - node0;
        int d2 = sorted_dst[e + 2] - node0, d3 = sorted_dst[e + 3] - node0;
        float v0 = hin[(size_t)s0 * DIM + lane];
        float v1 = hin[(size_t)s1 * DIM + lane];
        float v2 = hin[(size_t)s2 * DIM + lane];
        float v3 = hin[(size_t)s3 * DIM + lane];
        atomicAdd(&agg_s[d0 * 65 + lane], v0);
        atomicAdd(&agg_s[d1 * 65 + lane], v1);
        atomicAdd(&agg_s[d2 * 65 + lane], v2);
        atomicAdd(&agg_s[d3 * 65 + lane], v3);
    }
    for (; e < wend; ++e) {
        int s0 = sorted_src[e];
        int d0 = sorted_dst[e] - node0;
        float v0 = hin[(size_t)s0 * DIM + lane];
        atomicAdd(&agg_s[d0 * 65 + lane], v0);
    }
    __syncthreads();

    // Phase B
    int n = node0 + tid;
    if (n >= N_NODES) return;
    float out[DIM];
#pragma unroll
    for (int d = 0; d < DIM; ++d) out[d] = brel[d];

    const float4* hp = reinterpret_cast<const float4*>(hin + (size_t)n * DIM);
    const float* aggr = &agg_s[tid * 65];
    for (int kk = 0; kk < DIM / 4; ++kk) {
        float4 xv = hp[kk];  // own row, L1-resident
        float xa[4] = {xv.x, xv.y, xv.z, xv.w};
#pragma unroll
        for (int c = 0; c < 4; ++c) {
            int k = 4 * kk + c;
            float a = aggr[k];       // LDS broadcast-free (stride-65 pad)
            float xc = xa[c];
#pragma unroll
            for (int d = 0; d < DIM; ++d) {
                // weights are wave-uniform -> scalar-cache loads
                out[d] = fmaf(a, Wrel[k * DIM + d], fmaf(xc, Wroot[k * DIM + d], out[d]));
            }
        }
    }

    float4* op = reinterpret_cast<float4*>(hout + (size_t)n * DIM);
#pragma unroll
    for (int j = 0; j < DIM / 4; ++j) {
        float4 v;
        v.x = fmaxf(out[4 * j + 0], 0.f);
        v.y = fmaxf(out[4 * j + 1], 0.f);
        v.z = fmaxf(out[4 * j + 2], 0.f);
        v.w = fmaxf(out[4 * j + 3], 0.f);
        op[j] = v;
    }
}

// ---------------- global add pool ----------------
__global__ void pool_kernel(const float* __restrict__ h, const int* __restrict__ batch,
                            float* __restrict__ g) {
    int gtid = blockIdx.x * blockDim.x + threadIdx.x;
    int wid = gtid >> 6;
    int lane = gtid & 63;
    int nw = (gridDim.x * blockDim.x) >> 6;
    for (int n = wid; n < N_NODES; n += nw) {
        int b = batch[n];  // wave-uniform
        atomicAdd(&g[(size_t)b * DIM + lane], h[(size_t)n * DIM + lane]);
    }
}

// ---------------- classifier head ----------------
__global__ __launch_bounds__(256) void head_kernel(
    const float* __restrict__ g, const float* __restrict__ W1, const float* __restrict__ b1,
    const float* __restrict__ W2, const float* __restrict__ b2, float* __restrict__ y) {
    int gid = blockIdx.x * blockDim.x + threadIdx.x;
    if (gid >= N_GRAPHS) return;
    float t[DIM];
#pragma unroll
    for (int d = 0; d < DIM; ++d) t[d] = b1[d];
    const float4* gp = reinterpret_cast<const float4*>(g + (size_t)gid * DIM);
    for (int kk = 0; kk < DIM / 4; ++kk) {
        float4 gv = gp[kk];
        float ga[4] = {gv.x, gv.y, gv.z, gv.w};
#pragma unroll
        for (int c = 0; c < 4; ++c) {
            int k = 4 * kk + c;
            float v = ga[c];
#pragma unroll
            for (int d = 0; d < DIM; ++d) t[d] = fmaf(v, W1[k * DIM + d], t[d]);
        }
    }
#pragma unroll
    for (int d = 0; d < DIM; ++d) t[d] = fmaxf(t[d], 0.f);
    for (int o = 0; o < OUT_DIM; ++o) {
        float acc = b2[o];
#pragma unroll
        for (int d = 0; d < DIM; ++d) acc = fmaf(t[d], W2[d * OUT_DIM + o], acc);
        y[(size_t)gid * OUT_DIM + o] = acc;
    }
}

extern "C" void kernel_launch(void* const* d_in, const int* in_sizes, int n_in,
                              void* d_out, int out_size, void* d_ws, size_t ws_size,
                              hipStream_t stream) {
    const float* x     = (const float*)d_in[0];
    const int*   eidx  = (const int*)d_in[1];
    const int*   batch = (const int*)d_in[2];
    const float* Wrel  = (const float*)d_in[3];
    const float* brel  = (const float*)d_in[4];
    const float* Wroot = (const float*)d_in[5];
    const float* W1    = (const float*)d_in[6];
    const float* b1    = (const float*)d_in[7];
    const float* W2    = (const float*)d_in[8];
    const float* b2    = (const float*)d_in[9];
    float* y = (float*)d_out;

    char* ws = (char*)d_ws;
    const size_t HBYTES = (size_t)N_NODES * DIM * sizeof(float);  // 25.6 MB
    size_t off = 0;
    float* hA = (float*)(ws + off); off += HBYTES;
    float* hB = (float*)(ws + off); off += HBYTES;
    int* row_ptr = (int*)(ws + off); off += (((size_t)(N_NODES + 1) * 4 + 255) / 256) * 256;
    int* cursor  = (int*)(ws + off); off += (((size_t)N_NODES * 4 + 255) / 256) * 256;
    int* sorted_src = (int*)(ws + off); off += (size_t)N_EDGES * 4;
    int* sorted_dst = (int*)(ws + off); off += (size_t)N_EDGES * 4;
    float* g = (float*)(ws + off); off += (size_t)N_GRAPHS * DIM * 4;

    const int* src = eidx;
    const int* dst = eidx + N_EDGES;

    // CSR build (once per call, reused across 4 layers)
    hipMemsetAsync(row_ptr, 0, (size_t)(N_NODES + 1) * sizeof(int), stream);
    count_kernel<<<(N_EDGES + 255) / 256, 256, 0, stream>>>(dst, row_ptr);
    scan_kernel<<<1, 1024, 0, stream>>>(row_ptr, cursor);
    scatter_kernel<<<(N_EDGES + 255) / 256, 256, 0, stream>>>(src, dst, cursor, sorted_src, sorted_dst);

    // 4 GraphConv layers, ping-pong h buffers
    const float* hin = x;
    float* bufs[2] = {hA, hB};
    const int grid = (N_NODES + BN - 1) / BN;
    for (int l = 0; l < NLAYERS; ++l) {
        float* hout = bufs[l & 1];
        layer_kernel<<<grid, BN, 0, stream>>>(hin, hout,
                                              Wrel + (size_t)l * DIM * DIM,
                                              brel + (size_t)l * DIM,
                                              Wroot + (size_t)l * DIM * DIM,
                                              row_ptr, sorted_src, sorted_dst);
        hin = hout;
    }

    // global add pool
    hipMemsetAsync(g, 0, (size_t)N_GRAPHS * DIM * sizeof(float), stream);
    pool_kernel<<<1024, 256, 0, stream>>>(hin, batch, g);

    // head
    head_kernel<<<(N_GRAPHS + 255) / 256, 256, 0, stream>>>(g, W1, b1, W2, b2, y);
}

// Round 2
// 2011.559 us; speedup vs baseline: 1.2661x; 1.2661x over previous
//
#include <hip/hip_runtime.h>

#define N_NODES 100000
#define N_EDGES 1000000
#define DIM 64
#define N_GRAPHS 1024
#define OUT_DIM 16
#define NLAYERS 4

#define BN 64        // nodes per block in layer kernel
#define BLOCK 256    // 4 waves
#define SA 65        // agg_s row stride (floats): (lane+k)%32 -> 2-way, free
#define SX 68        // x_s row stride: mult of 4 for float4 LDS ops; 17*lane%32 -> 2-way

// ---------------- CSR build ----------------
__global__ void count_kernel(const int* __restrict__ dst, int* __restrict__ counts) {
    int e = blockIdx.x * blockDim.x + threadIdx.x;
    if (e < N_EDGES) atomicAdd(&counts[dst[e]], 1);
}

__global__ __launch_bounds__(1024) void scan_kernel(int* __restrict__ row_ptr, int* __restrict__ cursor) {
    __shared__ int part[1024];
    const int T = 1024;
    const int C = (N_NODES + T - 1) / T;  // 98
    int t = threadIdx.x;
    int beg = t * C;
    int end = min(beg + C, N_NODES);
    int sum = 0;
    for (int i = beg; i < end; ++i) sum += row_ptr[i];
    part[t] = sum;
    __syncthreads();
    for (int off = 1; off < T; off <<= 1) {
        int v = (t >= off) ? part[t - off] : 0;
        __syncthreads();
        part[t] += v;
        __syncthreads();
    }
    int run = (t > 0) ? part[t - 1] : 0;
    for (int i = beg; i < end; ++i) {
        int c = row_ptr[i];
        row_ptr[i] = run;
        cursor[i] = run;
        run += c;
    }
    if (t == T - 1) row_ptr[N_NODES] = part[T - 1];
}

__global__ void scatter_kernel(const int* __restrict__ src, const int* __restrict__ dst,
                               int* __restrict__ cursor, int2* __restrict__ edges) {
    int e = blockIdx.x * blockDim.x + threadIdx.x;
    if (e < N_EDGES) {
        int d = dst[e];
        int pos = atomicAdd(&cursor[d], 1);
        edges[pos] = make_int2(src[e], d);  // one 8B store instead of two scattered 4B
    }
}

// ---------------- fused GraphConv layer ----------------
// Phase A: 4 waves edge-parallel gather -> LDS atomics (stride 65: 2-way alias, free).
//          x rows staged to LDS via coalesced float4.
// Phase B: wave q computes dims [16q,16q+16) for all 64 nodes; weights are
//          wave-uniform -> scalar loads; agg/x from LDS; 16 accumulators/thread.
// Store:   results transposed through x_s (free after use) -> float4 coalesced.
__global__ __launch_bounds__(BLOCK) void layer_kernel(
    const float* __restrict__ hin, float* __restrict__ hout,
    const float* __restrict__ Wrel, const float* __restrict__ brel,
    const float* __restrict__ Wroot,
    const int* __restrict__ row_ptr, const int2* __restrict__ edges) {
    __shared__ float agg_s[BN * SA];
    __shared__ float x_s[BN * SX];
    const int tid = threadIdx.x;
    const int lane = tid & 63;
    const int wave = __builtin_amdgcn_readfirstlane(tid >> 6);
    const int node0 = blockIdx.x * BN;
    const int nvalid = min(BN, N_NODES - node0);

    // zero agg
    for (int i = tid; i < BN * SA; i += BLOCK) agg_s[i] = 0.f;
    // stage own x rows (coalesced float4 reads)
    for (int i = tid; i < nvalid * (DIM / 4); i += BLOCK) {
        int nl = i >> 4;
        int c = i & 15;
        float4 v = reinterpret_cast<const float4*>(hin)[(size_t)(node0 + nl) * (DIM / 4) + c];
        reinterpret_cast<float4*>(x_s)[nl * (SX / 4) + c] = v;
    }
    __syncthreads();

    // Phase A: edge gather
    const int ebeg = row_ptr[node0];
    const int eend = row_ptr[node0 + nvalid];
    const int total = eend - ebeg;
    const int chunk = (total + 3) / 4;
    int wbeg = ebeg + wave * chunk;
    int wend = min(wbeg + chunk, eend);

    int e = wbeg;
    for (; e + 8 <= wend; e += 8) {
        int2 ed[8];
#pragma unroll
        for (int i = 0; i < 8; ++i) ed[i] = edges[e + i];  // e wave-uniform
        float v[8];
#pragma unroll
        for (int i = 0; i < 8; ++i) v[i] = hin[(size_t)ed[i].x * DIM + lane];  // 8 coalesced 256B rows in flight
#pragma unroll
        for (int i = 0; i < 8; ++i) atomicAdd(&agg_s[(ed[i].y - node0) * SA + lane], v[i]);
    }
    for (; e < wend; ++e) {
        int2 ed = edges[e];
        atomicAdd(&agg_s[(ed.y - node0) * SA + lane], hin[(size_t)ed.x * DIM + lane]);
    }
    __syncthreads();

    // Phase B: node = lane, dim-quarter = wave
    const int d0 = wave * 16;
    float out[16];
#pragma unroll
    for (int j = 0; j < 16; ++j) out[j] = brel[d0 + j];  // uniform -> scalar
    const float* ar = &agg_s[lane * SA];
    const float* xr = &x_s[lane * SX];
    for (int k = 0; k < DIM; ++k) {
        float a = ar[k];                     // LDS, 2-way alias (free)
        float xv = xr[k];
        const float* wr = &Wrel[k * DIM + d0];   // wave-uniform -> s_load_dwordx
        const float* wo = &Wroot[k * DIM + d0];
#pragma unroll
        for (int j = 0; j < 16; ++j)
            out[j] = fmaf(a, wr[j], fmaf(xv, wo[j], out[j]));
    }

    __syncthreads();  // all waves done reading x_s
    if (lane < nvalid) {
#pragma unroll
        for (int j = 0; j < 16; ++j) x_s[lane * SX + d0 + j] = fmaxf(out[j], 0.f);
    }
    __syncthreads();

    // coalesced float4 store
    for (int i = tid; i < nvalid * (DIM / 4); i += BLOCK) {
        int nl = i >> 4;
        int c = i & 15;
        float4 v = reinterpret_cast<const float4*>(x_s)[nl * (SX / 4) + c];
        reinterpret_cast<float4*>(hout)[(size_t)(node0 + nl) * (DIM / 4) + c] = v;
    }
}

// ---------------- global add pool ----------------
// batch is sorted: each wave takes a contiguous node chunk, run-accumulates in
// registers, one global atomic per run boundary (~2k atomics total vs 100k).
__global__ __launch_bounds__(256) void pool_kernel(const float* __restrict__ h,
                                                   const int* __restrict__ batch,
                                                   float* __restrict__ g) {
    int gtid = blockIdx.x * blockDim.x + threadIdx.x;
    int w = gtid >> 6;
    int lane = gtid & 63;
    const int NW = 1024;
    const int CH = (N_NODES + NW - 1) / NW;  // 98
    int nb = w * CH;
    int ne = min(nb + CH, N_NODES);
    if (nb >= ne) return;
    float acc = 0.f;
    int cur = batch[nb];
    for (int n = nb; n < ne; ++n) {
        int b = batch[n];  // wave-uniform broadcast
        if (b != cur) {
            atomicAdd(&g[(size_t)cur * DIM + lane], acc);
            acc = 0.f;
            cur = b;
        }
        acc += h[(size_t)n * DIM + lane];
    }
    atomicAdd(&g[(size_t)cur * DIM + lane], acc);
}

// ---------------- classifier head ----------------
__global__ __launch_bounds__(256) void head_kernel(
    const float* __restrict__ g, const float* __restrict__ W1, const float* __restrict__ b1,
    const float* __restrict__ W2, const float* __restrict__ b2, float* __restrict__ y) {
    int gid = blockIdx.x * blockDim.x + threadIdx.x;
    if (gid >= N_GRAPHS) return;
    float t[DIM];
#pragma unroll
    for (int d = 0; d < DIM; ++d) t[d] = b1[d];
    const float4* gp = reinterpret_cast<const float4*>(g + (size_t)gid * DIM);
    for (int kk = 0; kk < DIM / 4; ++kk) {
        float4 gv = gp[kk];
        float ga[4] = {gv.x, gv.y, gv.z, gv.w};
#pragma unroll
        for (int c = 0; c < 4; ++c) {
            int k = 4 * kk + c;
            float v = ga[c];
#pragma unroll
            for (int d = 0; d < DIM; ++d) t[d] = fmaf(v, W1[k * DIM + d], t[d]);
        }
    }
#pragma unroll
    for (int d = 0; d < DIM; ++d) t[d] = fmaxf(t[d], 0.f);
    for (int o = 0; o < OUT_DIM; ++o) {
        float acc = b2[o];
#pragma unroll
        for (int d = 0; d < DIM; ++d) acc = fmaf(t[d], W2[d * OUT_DIM + o], acc);
        y[(size_t)gid * OUT_DIM + o] = acc;
    }
}

extern "C" void kernel_launch(void* const* d_in, const int* in_sizes, int n_in,
                              void* d_out, int out_size, void* d_ws, size_t ws_size,
                              hipStream_t stream) {
    const float* x     = (const float*)d_in[0];
    const int*   eidx  = (const int*)d_in[1];
    const int*   batch = (const int*)d_in[2];
    const float* Wrel  = (const float*)d_in[3];
    const float* brel  = (const float*)d_in[4];
    const float* Wroot = (const float*)d_in[5];
    const float* W1    = (const float*)d_in[6];
    const float* b1    = (const float*)d_in[7];
    const float* W2    = (const float*)d_in[8];
    const float* b2    = (const float*)d_in[9];
    float* y = (float*)d_out;

    char* ws = (char*)d_ws;
    const size_t HBYTES = (size_t)N_NODES * DIM * sizeof(float);  // 25.6 MB
    size_t off = 0;
    float* hA = (float*)(ws + off); off += HBYTES;
    float* hB = (float*)(ws + off); off += HBYTES;
    int* row_ptr = (int*)(ws + off); off += (((size_t)(N_NODES + 1) * 4 + 255) / 256) * 256;
    int* cursor  = (int*)(ws + off); off += (((size_t)N_NODES * 4 + 255) / 256) * 256;
    int2* edges  = (int2*)(ws + off); off += (size_t)N_EDGES * 8;
    float* g = (float*)(ws + off); off += (size_t)N_GRAPHS * DIM * 4;

    const int* src = eidx;
    const int* dst = eidx + N_EDGES;

    // CSR build (once, reused across 4 layers)
    hipMemsetAsync(row_ptr, 0, (size_t)(N_NODES + 1) * sizeof(int), stream);
    count_kernel<<<(N_EDGES + 255) / 256, 256, 0, stream>>>(dst, row_ptr);
    scan_kernel<<<1, 1024, 0, stream>>>(row_ptr, cursor);
    scatter_kernel<<<(N_EDGES + 255) / 256, 256, 0, stream>>>(src, dst, cursor, edges);

    // 4 GraphConv layers, ping-pong
    const float* hin = x;
    float* bufs[2] = {hA, hB};
    const int grid = (N_NODES + BN - 1) / BN;  // 1563
    for (int l = 0; l < NLAYERS; ++l) {
        float* hout = bufs[l & 1];
        layer_kernel<<<grid, BLOCK, 0, stream>>>(hin, hout,
                                                 Wrel + (size_t)l * DIM * DIM,
                                                 brel + (size_t)l * DIM,
                                                 Wroot + (size_t)l * DIM * DIM,
                                                 row_ptr, edges);
        hin = hout;
    }

    // global add pool
    hipMemsetAsync(g, 0, (size_t)N_GRAPHS * DIM * sizeof(float), stream);
    pool_kernel<<<256, 256, 0, stream>>>(hin, batch, g);

    // head
    head_kernel<<<(N_GRAPHS + 255) / 256, 256, 0, stream>>>(g, W1, b1, W2, b2, y);
}

// Round 3
// 2010.881 us; speedup vs baseline: 1.2665x; 1.0003x over previous
//
#include <hip/hip_runtime.h>

#define N_NODES 100000
#define N_EDGES 1000000
#define DIM 64
#define N_GRAPHS 1024
#define OUT_DIM 16
#define NLAYERS 4

#define BN 64        // nodes per block in layer kernel
#define BLOCK 512    // 8 waves
#define NWAVES 8
#define SA 65        // agg_s row stride (floats): 65%32==1 -> 2-way alias, free
#define SX 68        // x_s row stride: mult of 4 for float4 LDS ops

// ---------------- CSR build ----------------
__global__ void count_kernel(const int* __restrict__ dst, int* __restrict__ counts) {
    int e = blockIdx.x * blockDim.x + threadIdx.x;
    if (e < N_EDGES) atomicAdd(&counts[dst[e]], 1);
}

__global__ __launch_bounds__(1024) void scan_kernel(int* __restrict__ row_ptr, int* __restrict__ cursor) {
    __shared__ int part[1024];
    const int T = 1024;
    const int C = (N_NODES + T - 1) / T;  // 98
    int t = threadIdx.x;
    int beg = t * C;
    int end = min(beg + C, N_NODES);
    int sum = 0;
    for (int i = beg; i < end; ++i) sum += row_ptr[i];
    part[t] = sum;
    __syncthreads();
    for (int off = 1; off < T; off <<= 1) {
        int v = (t >= off) ? part[t - off] : 0;
        __syncthreads();
        part[t] += v;
        __syncthreads();
    }
    int run = (t > 0) ? part[t - 1] : 0;
    for (int i = beg; i < end; ++i) {
        int c = row_ptr[i];
        row_ptr[i] = run;
        cursor[i] = run;
        run += c;
    }
    if (t == T - 1) row_ptr[N_NODES] = part[T - 1];
}

__global__ void scatter_kernel(const int* __restrict__ src, const int* __restrict__ dst,
                               int* __restrict__ cursor, int2* __restrict__ edges) {
    int e = blockIdx.x * blockDim.x + threadIdx.x;
    if (e < N_EDGES) {
        int d = dst[e];
        int pos = atomicAdd(&cursor[d], 1);
        edges[pos] = make_int2(src[e], d);
    }
}

// ---------------- fused GraphConv layer ----------------
// Phase A: 8 waves, lane-quad gather: 16 lanes per src row, float4/lane ->
//          each VMEM instruction brings 4 complete rows (1KB). 8-deep unroll
//          = 32 edges/iter/wave, 8KB in flight per wave.
// Phase B: wave q computes dims [8q,8q+8) for all 64 nodes; weights wave-uniform
//          -> scalar loads; agg/x from LDS.
__global__ __launch_bounds__(BLOCK) void layer_kernel(
    const float* __restrict__ hin, float* __restrict__ hout,
    const float* __restrict__ Wrel, const float* __restrict__ brel,
    const float* __restrict__ Wroot,
    const int* __restrict__ row_ptr, const int2* __restrict__ edges) {
    __shared__ float agg_s[BN * SA];
    __shared__ float x_s[BN * SX];
    const int tid = threadIdx.x;
    const int lane = tid & 63;
    const int wave = __builtin_amdgcn_readfirstlane(tid >> 6);
    const int grp = lane >> 4;        // which of 4 rows this lane helps gather
    const int gl = lane & 15;         // position within row (float4 granules)
    const int node0 = blockIdx.x * BN;
    const int nvalid = min(BN, N_NODES - node0);

    for (int i = tid; i < BN * SA; i += BLOCK) agg_s[i] = 0.f;
    for (int i = tid; i < nvalid * (DIM / 4); i += BLOCK) {
        int nl = i >> 4;
        int c = i & 15;
        float4 v = reinterpret_cast<const float4*>(hin)[(size_t)(node0 + nl) * (DIM / 4) + c];
        reinterpret_cast<float4*>(x_s)[nl * (SX / 4) + c] = v;
    }
    __syncthreads();

    // Phase A
    const int ebeg = row_ptr[node0];
    const int eend = row_ptr[node0 + nvalid];
    const int total = eend - ebeg;
    const int chunk = (total + NWAVES - 1) / NWAVES;
    int wbeg = ebeg + wave * chunk;
    int wend = min(wbeg + chunk, eend);

    const float4* hin4 = reinterpret_cast<const float4*>(hin);
    int e = wbeg;
    for (; e + 32 <= wend; e += 32) {
        int2 ed[8];
#pragma unroll
        for (int i = 0; i < 8; ++i) ed[i] = edges[e + 4 * i + grp];  // 4 distinct addrs/instr
        float4 v[8];
#pragma unroll
        for (int i = 0; i < 8; ++i) v[i] = hin4[(size_t)ed[i].x * (DIM / 4) + gl];  // 1KB/instr
#pragma unroll
        for (int i = 0; i < 8; ++i) {
            float* base = &agg_s[(ed[i].y - node0) * SA + gl * 4];
            atomicAdd(base + 0, v[i].x);
            atomicAdd(base + 1, v[i].y);
            atomicAdd(base + 2, v[i].z);
            atomicAdd(base + 3, v[i].w);
        }
    }
    for (; e + 4 <= wend; e += 4) {
        int2 ed = edges[e + grp];
        float4 v = hin4[(size_t)ed.x * (DIM / 4) + gl];
        float* base = &agg_s[(ed.y - node0) * SA + gl * 4];
        atomicAdd(base + 0, v.x);
        atomicAdd(base + 1, v.y);
        atomicAdd(base + 2, v.z);
        atomicAdd(base + 3, v.w);
    }
    if (e < wend) {
        int idx = e + grp;
        if (idx < wend) {
            int2 ed = edges[idx];
            float4 v = hin4[(size_t)ed.x * (DIM / 4) + gl];
            float* base = &agg_s[(ed.y - node0) * SA + gl * 4];
            atomicAdd(base + 0, v.x);
            atomicAdd(base + 1, v.y);
            atomicAdd(base + 2, v.z);
            atomicAdd(base + 3, v.w);
        }
    }
    __syncthreads();

    // Phase B: node = lane, dim-octet = wave
    const int d0 = wave * 8;
    float out[8];
#pragma unroll
    for (int j = 0; j < 8; ++j) out[j] = brel[d0 + j];  // uniform -> scalar
    const float* ar = &agg_s[lane * SA];
    const float* xr = &x_s[lane * SX];
    for (int k = 0; k < DIM; ++k) {
        float a = ar[k];
        float xv = xr[k];
        const float* wr = &Wrel[k * DIM + d0];   // wave-uniform -> s_load
        const float* wo = &Wroot[k * DIM + d0];
#pragma unroll
        for (int j = 0; j < 8; ++j)
            out[j] = fmaf(a, wr[j], fmaf(xv, wo[j], out[j]));
    }

    __syncthreads();  // all waves done reading x_s
    if (lane < nvalid) {
#pragma unroll
        for (int j = 0; j < 8; ++j) x_s[lane * SX + d0 + j] = fmaxf(out[j], 0.f);
    }
    __syncthreads();

    for (int i = tid; i < nvalid * (DIM / 4); i += BLOCK) {
        int nl = i >> 4;
        int c = i & 15;
        float4 v = reinterpret_cast<const float4*>(x_s)[nl * (SX / 4) + c];
        reinterpret_cast<float4*>(hout)[(size_t)(node0 + nl) * (DIM / 4) + c] = v;
    }
}

// ---------------- global add pool ----------------
__global__ __launch_bounds__(256) void pool_kernel(const float* __restrict__ h,
                                                   const int* __restrict__ batch,
                                                   float* __restrict__ g) {
    int gtid = blockIdx.x * blockDim.x + threadIdx.x;
    int w = gtid >> 6;
    int lane = gtid & 63;
    const int NW = 1024;
    const int CH = (N_NODES + NW - 1) / NW;  // 98
    int nb = w * CH;
    int ne = min(nb + CH, N_NODES);
    if (nb >= ne) return;
    float acc = 0.f;
    int cur = batch[nb];
    for (int n = nb; n < ne; ++n) {
        int b = batch[n];  // wave-uniform broadcast
        if (b != cur) {
            atomicAdd(&g[(size_t)cur * DIM + lane], acc);
            acc = 0.f;
            cur = b;
        }
        acc += h[(size_t)n * DIM + lane];
    }
    atomicAdd(&g[(size_t)cur * DIM + lane], acc);
}

// ---------------- classifier head ----------------
__global__ __launch_bounds__(256) void head_kernel(
    const float* __restrict__ g, const float* __restrict__ W1, const float* __restrict__ b1,
    const float* __restrict__ W2, const float* __restrict__ b2, float* __restrict__ y) {
    int gid = blockIdx.x * blockDim.x + threadIdx.x;
    if (gid >= N_GRAPHS) return;
    float t[DIM];
#pragma unroll
    for (int d = 0; d < DIM; ++d) t[d] = b1[d];
    const float4* gp = reinterpret_cast<const float4*>(g + (size_t)gid * DIM);
    for (int kk = 0; kk < DIM / 4; ++kk) {
        float4 gv = gp[kk];
        float ga[4] = {gv.x, gv.y, gv.z, gv.w};
#pragma unroll
        for (int c = 0; c < 4; ++c) {
            int k = 4 * kk + c;
            float v = ga[c];
#pragma unroll
            for (int d = 0; d < DIM; ++d) t[d] = fmaf(v, W1[k * DIM + d], t[d]);
        }
    }
#pragma unroll
    for (int d = 0; d < DIM; ++d) t[d] = fmaxf(t[d], 0.f);
    for (int o = 0; o < OUT_DIM; ++o) {
        float acc = b2[o];
#pragma unroll
        for (int d = 0; d < DIM; ++d) acc = fmaf(t[d], W2[d * OUT_DIM + o], acc);
        y[(size_t)gid * OUT_DIM + o] = acc;
    }
}

extern "C" void kernel_launch(void* const* d_in, const int* in_sizes, int n_in,
                              void* d_out, int out_size, void* d_ws, size_t ws_size,
                              hipStream_t stream) {
    const float* x     = (const float*)d_in[0];
    const int*   eidx  = (const int*)d_in[1];
    const int*   batch = (const int*)d_in[2];
    const float* Wrel  = (const float*)d_in[3];
    const float* brel  = (const float*)d_in[4];
    const float* Wroot = (const float*)d_in[5];
    const float* W1    = (const float*)d_in[6];
    const float* b1    = (const float*)d_in[7];
    const float* W2    = (const float*)d_in[8];
    const float* b2    = (const float*)d_in[9];
    float* y = (float*)d_out;

    char* ws = (char*)d_ws;
    const size_t HBYTES = (size_t)N_NODES * DIM * sizeof(float);  // 25.6 MB
    size_t off = 0;
    float* hA = (float*)(ws + off); off += HBYTES;
    float* hB = (float*)(ws + off); off += HBYTES;
    int* row_ptr = (int*)(ws + off); off += (((size_t)(N_NODES + 1) * 4 + 255) / 256) * 256;
    int* cursor  = (int*)(ws + off); off += (((size_t)N_NODES * 4 + 255) / 256) * 256;
    int2* edges  = (int2*)(ws + off); off += (size_t)N_EDGES * 8;
    float* g = (float*)(ws + off); off += (size_t)N_GRAPHS * DIM * 4;

    const int* src = eidx;
    const int* dst = eidx + N_EDGES;

    // CSR build (once, reused across 4 layers)
    hipMemsetAsync(row_ptr, 0, (size_t)(N_NODES + 1) * sizeof(int), stream);
    count_kernel<<<(N_EDGES + 255) / 256, 256, 0, stream>>>(dst, row_ptr);
    scan_kernel<<<1, 1024, 0, stream>>>(row_ptr, cursor);
    scatter_kernel<<<(N_EDGES + 255) / 256, 256, 0, stream>>>(src, dst, cursor, edges);

    // 4 GraphConv layers, ping-pong
    const float* hin = x;
    float* bufs[2] = {hA, hB};
    const int grid = (N_NODES + BN - 1) / BN;  // 1563
    for (int l = 0; l < NLAYERS; ++l) {
        float* hout = bufs[l & 1];
        layer_kernel<<<grid, BLOCK, 0, stream>>>(hin, hout,
                                                 Wrel + (size_t)l * DIM * DIM,
                                                 brel + (size_t)l * DIM,
                                                 Wroot + (size_t)l * DIM * DIM,
                                                 row_ptr, edges);
        hin = hout;
    }

    // global add pool
    hipMemsetAsync(g, 0, (size_t)N_GRAPHS * DIM * sizeof(float), stream);
    pool_kernel<<<256, 256, 0, stream>>>(hin, batch, g);

    // head
    head_kernel<<<(N_GRAPHS + 255) / 256, 256, 0, stream>>>(g, W1, b1, W2, b2, y);
}

// Round 4
// 1843.216 us; speedup vs baseline: 1.3818x; 1.0910x over previous
//
#include <hip/hip_runtime.h>

#define N_NODES 100000
#define N_EDGES 1000000
#define DIM 64
#define N_GRAPHS 1024
#define OUT_DIM 16
#define NLAYERS 4

#define BN 64        // nodes per block in layer kernel
#define NB 1563      // ceil(N_NODES/BN)
#define NTILES 16    // src tiles per dst block; tile = 6250 rows = 1.6MB < 4MB L2
#define TILE 6250
#define NBKT (NB * NTILES)
#define BLOCK 512    // 8 waves
#define NWAVES 8
#define SA 65        // agg_s row stride: 65%32==1 -> 2-way alias, free
#define SX 68        // x_s row stride: mult of 4 for float4 LDS ops

// ---------------- bucketed CSR build ----------------
// bucket = (dst_block, src_tile): gives per-block contiguous edge ranges AND
// src-ascending sweep order -> device-wide moving window keeps gather L2-resident.
__global__ void count_kernel(const int* __restrict__ src, const int* __restrict__ dst,
                             int* __restrict__ counts) {
    int e = blockIdx.x * blockDim.x + threadIdx.x;
    if (e < N_EDGES) {
        int bkt = (dst[e] >> 6) * NTILES + src[e] / TILE;
        atomicAdd(&counts[bkt], 1);
    }
}

__global__ __launch_bounds__(1024) void scan_kernel(int* __restrict__ bptr, int* __restrict__ cursor) {
    __shared__ int part[1024];
    const int T = 1024;
    const int C = (NBKT + T - 1) / T;  // 25
    int t = threadIdx.x;
    int beg = t * C;
    int end = min(beg + C, NBKT);
    int sum = 0;
    for (int i = beg; i < end; ++i) sum += bptr[i];
    part[t] = sum;
    __syncthreads();
    for (int off = 1; off < T; off <<= 1) {
        int v = (t >= off) ? part[t - off] : 0;
        __syncthreads();
        part[t] += v;
        __syncthreads();
    }
    int run = (t > 0) ? part[t - 1] : 0;
    for (int i = beg; i < end; ++i) {
        int c = bptr[i];
        bptr[i] = run;
        cursor[i] = run;
        run += c;
    }
    if (t == T - 1) bptr[NBKT] = part[T - 1];
}

__global__ void scatter_kernel(const int* __restrict__ src, const int* __restrict__ dst,
                               int* __restrict__ cursor, int* __restrict__ edges) {
    int e = blockIdx.x * blockDim.x + threadIdx.x;
    if (e < N_EDGES) {
        int s = src[e], d = dst[e];
        int bkt = (d >> 6) * NTILES + s / TILE;
        int pos = atomicAdd(&cursor[bkt], 1);
        edges[pos] = ((d & 63) << 17) | s;  // 6b dst_local | 17b src, one 4B store
    }
}

// ---------------- fused GraphConv layer ----------------
// Phase A: 8 waves, lane-quad gather: 16 lanes per src row, float4/lane ->
//          each VMEM instruction brings 4 complete rows (1KB). Edges arrive
//          src-tile-ordered -> concurrent blocks sweep the same L2 window.
// Phase B: wave q computes dims [8q,8q+8) for all 64 nodes; weights wave-uniform.
__global__ __launch_bounds__(BLOCK) void layer_kernel(
    const float* __restrict__ hin, float* __restrict__ hout,
    const float* __restrict__ Wrel, const float* __restrict__ brel,
    const float* __restrict__ Wroot,
    const int* __restrict__ bptr, const int* __restrict__ edges) {
    __shared__ float agg_s[BN * SA];
    __shared__ float x_s[BN * SX];
    const int tid = threadIdx.x;
    const int lane = tid & 63;
    const int wave = __builtin_amdgcn_readfirstlane(tid >> 6);
    const int grp = lane >> 4;        // which of 4 rows this lane helps gather
    const int gl = lane & 15;         // float4 position within row
    const int node0 = blockIdx.x * BN;
    const int nvalid = min(BN, N_NODES - node0);

    for (int i = tid; i < BN * SA; i += BLOCK) agg_s[i] = 0.f;
    for (int i = tid; i < nvalid * (DIM / 4); i += BLOCK) {
        int nl = i >> 4;
        int c = i & 15;
        float4 v = reinterpret_cast<const float4*>(hin)[(size_t)(node0 + nl) * (DIM / 4) + c];
        reinterpret_cast<float4*>(x_s)[nl * (SX / 4) + c] = v;
    }
    __syncthreads();

    // Phase A
    const int ebeg = bptr[blockIdx.x * NTILES];
    const int eend = bptr[blockIdx.x * NTILES + NTILES];
    const int total = eend - ebeg;
    const int chunk = (total + NWAVES - 1) / NWAVES;
    int wbeg = ebeg + wave * chunk;
    int wend = min(wbeg + chunk, eend);

    const float4* hin4 = reinterpret_cast<const float4*>(hin);
    int e = wbeg;
    for (; e + 32 <= wend; e += 32) {
        int p[8];
#pragma unroll
        for (int i = 0; i < 8; ++i) p[i] = edges[e + 4 * i + grp];  // 4 distinct ints/instr
        float4 v[8];
#pragma unroll
        for (int i = 0; i < 8; ++i) v[i] = hin4[(size_t)(p[i] & 0x1FFFF) * (DIM / 4) + gl];
#pragma unroll
        for (int i = 0; i < 8; ++i) {
            float* base = &agg_s[(p[i] >> 17) * SA + gl * 4];
            atomicAdd(base + 0, v[i].x);
            atomicAdd(base + 1, v[i].y);
            atomicAdd(base + 2, v[i].z);
            atomicAdd(base + 3, v[i].w);
        }
    }
    for (; e + 4 <= wend; e += 4) {
        int p = edges[e + grp];
        float4 v = hin4[(size_t)(p & 0x1FFFF) * (DIM / 4) + gl];
        float* base = &agg_s[(p >> 17) * SA + gl * 4];
        atomicAdd(base + 0, v.x);
        atomicAdd(base + 1, v.y);
        atomicAdd(base + 2, v.z);
        atomicAdd(base + 3, v.w);
    }
    if (e < wend) {
        int idx = e + grp;
        if (idx < wend) {
            int p = edges[idx];
            float4 v = hin4[(size_t)(p & 0x1FFFF) * (DIM / 4) + gl];
            float* base = &agg_s[(p >> 17) * SA + gl * 4];
            atomicAdd(base + 0, v.x);
            atomicAdd(base + 1, v.y);
            atomicAdd(base + 2, v.z);
            atomicAdd(base + 3, v.w);
        }
    }
    __syncthreads();

    // Phase B: node = lane, dim-octet = wave
    const int d0 = wave * 8;
    float out[8];
#pragma unroll
    for (int j = 0; j < 8; ++j) out[j] = brel[d0 + j];  // uniform -> scalar
    const float* ar = &agg_s[lane * SA];
    const float* xr = &x_s[lane * SX];
    for (int k = 0; k < DIM; ++k) {
        float a = ar[k];
        float xv = xr[k];
        const float* wr = &Wrel[k * DIM + d0];   // wave-uniform -> s_load
        const float* wo = &Wroot[k * DIM + d0];
#pragma unroll
        for (int j = 0; j < 8; ++j)
            out[j] = fmaf(a, wr[j], fmaf(xv, wo[j], out[j]));
    }

    __syncthreads();  // all waves done reading x_s
    if (lane < nvalid) {
#pragma unroll
        for (int j = 0; j < 8; ++j) x_s[lane * SX + d0 + j] = fmaxf(out[j], 0.f);
    }
    __syncthreads();

    for (int i = tid; i < nvalid * (DIM / 4); i += BLOCK) {
        int nl = i >> 4;
        int c = i & 15;
        float4 v = reinterpret_cast<const float4*>(x_s)[nl * (SX / 4) + c];
        reinterpret_cast<float4*>(hout)[(size_t)(node0 + nl) * (DIM / 4) + c] = v;
    }
}

// ---------------- global add pool ----------------
__global__ __launch_bounds__(256) void pool_kernel(const float* __restrict__ h,
                                                   const int* __restrict__ batch,
                                                   float* __restrict__ g) {
    int gtid = blockIdx.x * blockDim.x + threadIdx.x;
    int w = gtid >> 6;
    int lane = gtid & 63;
    const int NW = 1024;
    const int CH = (N_NODES + NW - 1) / NW;  // 98
    int nb = w * CH;
    int ne = min(nb + CH, N_NODES);
    if (nb >= ne) return;
    float acc = 0.f;
    int cur = batch[nb];
    for (int n = nb; n < ne; ++n) {
        int b = batch[n];  // wave-uniform broadcast
        if (b != cur) {
            atomicAdd(&g[(size_t)cur * DIM + lane], acc);
            acc = 0.f;
            cur = b;
        }
        acc += h[(size_t)n * DIM + lane];
    }
    atomicAdd(&g[(size_t)cur * DIM + lane], acc);
}

// ---------------- classifier head ----------------
__global__ __launch_bounds__(256) void head_kernel(
    const float* __restrict__ g, const float* __restrict__ W1, const float* __restrict__ b1,
    const float* __restrict__ W2, const float* __restrict__ b2, float* __restrict__ y) {
    int gid = blockIdx.x * blockDim.x + threadIdx.x;
    if (gid >= N_GRAPHS) return;
    float t[DIM];
#pragma unroll
    for (int d = 0; d < DIM; ++d) t[d] = b1[d];
    const float4* gp = reinterpret_cast<const float4*>(g + (size_t)gid * DIM);
    for (int kk = 0; kk < DIM / 4; ++kk) {
        float4 gv = gp[kk];
        float ga[4] = {gv.x, gv.y, gv.z, gv.w};
#pragma unroll
        for (int c = 0; c < 4; ++c) {
            int k = 4 * kk + c;
            float v = ga[c];
#pragma unroll
            for (int d = 0; d < DIM; ++d) t[d] = fmaf(v, W1[k * DIM + d], t[d]);
        }
    }
#pragma unroll
    for (int d = 0; d < DIM; ++d) t[d] = fmaxf(t[d], 0.f);
    for (int o = 0; o < OUT_DIM; ++o) {
        float acc = b2[o];
#pragma unroll
        for (int d = 0; d < DIM; ++d) acc = fmaf(t[d], W2[d * OUT_DIM + o], acc);
        y[(size_t)gid * OUT_DIM + o] = acc;
    }
}

extern "C" void kernel_launch(void* const* d_in, const int* in_sizes, int n_in,
                              void* d_out, int out_size, void* d_ws, size_t ws_size,
                              hipStream_t stream) {
    const float* x     = (const float*)d_in[0];
    const int*   eidx  = (const int*)d_in[1];
    const int*   batch = (const int*)d_in[2];
    const float* Wrel  = (const float*)d_in[3];
    const float* brel  = (const float*)d_in[4];
    const float* Wroot = (const float*)d_in[5];
    const float* W1    = (const float*)d_in[6];
    const float* b1    = (const float*)d_in[7];
    const float* W2    = (const float*)d_in[8];
    const float* b2    = (const float*)d_in[9];
    float* y = (float*)d_out;

    char* ws = (char*)d_ws;
    const size_t HBYTES = (size_t)N_NODES * DIM * sizeof(float);  // 25.6 MB
    size_t off = 0;
    float* hA = (float*)(ws + off); off += HBYTES;
    float* hB = (float*)(ws + off); off += HBYTES;
    int* bptr   = (int*)(ws + off); off += (((size_t)(NBKT + 1) * 4 + 255) / 256) * 256;
    int* cursor = (int*)(ws + off); off += (((size_t)NBKT * 4 + 255) / 256) * 256;
    int* edges  = (int*)(ws + off); off += (size_t)N_EDGES * 4;
    float* g = (float*)(ws + off); off += (size_t)N_GRAPHS * DIM * 4;

    const int* src = eidx;
    const int* dst = eidx + N_EDGES;

    // bucketed CSR build (once, reused across 4 layers)
    hipMemsetAsync(bptr, 0, (size_t)(NBKT + 1) * sizeof(int), stream);
    count_kernel<<<(N_EDGES + 255) / 256, 256, 0, stream>>>(src, dst, bptr);
    scan_kernel<<<1, 1024, 0, stream>>>(bptr, cursor);
    scatter_kernel<<<(N_EDGES + 255) / 256, 256, 0, stream>>>(src, dst, cursor, edges);

    // 4 GraphConv layers, ping-pong
    const float* hin = x;
    float* bufs[2] = {hA, hB};
    for (int l = 0; l < NLAYERS; ++l) {
        float* hout = bufs[l & 1];
        layer_kernel<<<NB, BLOCK, 0, stream>>>(hin, hout,
                                               Wrel + (size_t)l * DIM * DIM,
                                               brel + (size_t)l * DIM,
                                               Wroot + (size_t)l * DIM * DIM,
                                               bptr, edges);
        hin = hout;
    }

    // global add pool
    hipMemsetAsync(g, 0, (size_t)N_GRAPHS * DIM * sizeof(float), stream);
    pool_kernel<<<256, 256, 0, stream>>>(hin, batch, g);

    // head
    head_kernel<<<(N_GRAPHS + 255) / 256, 256, 0, stream>>>(g, W1, b1, W2, b2, y);
}

// Round 5
// 775.742 us; speedup vs baseline: 3.2832x; 2.3761x over previous
//
#include <hip/hip_runtime.h>

#define N_NODES 100000
#define N_EDGES 1000000
#define DIM 64
#define N_GRAPHS 1024
#define OUT_DIM 16
#define NLAYERS 4

#define BN 64        // nodes per block in layer kernel
#define NB 1563      // ceil(N_NODES/BN)
#define BLOCK 512    // 8 waves
#define NWAVES 8
#define RPW 8        // dst rows owned per wave (BN/NWAVES) -> no atomics needed
#define SA 65        // agg_s row stride: 65%32==1 -> 2-way alias, free
#define SX 68        // x_s row stride: mult of 4 for float4 LDS ops

// ---------------- CSR build (node-granular, payload = src only) ----------------
__global__ void count_kernel(const int* __restrict__ dst, int* __restrict__ counts) {
    int e = blockIdx.x * blockDim.x + threadIdx.x;
    if (e < N_EDGES) atomicAdd(&counts[dst[e]], 1);  // int atomic: native, fast
}

__global__ __launch_bounds__(1024) void scan_kernel(int* __restrict__ row_ptr, int* __restrict__ cursor) {
    __shared__ int part[1024];
    const int T = 1024;
    const int C = (N_NODES + T - 1) / T;  // 98
    int t = threadIdx.x;
    int beg = t * C;
    int end = min(beg + C, N_NODES);
    int sum = 0;
    for (int i = beg; i < end; ++i) sum += row_ptr[i];
    part[t] = sum;
    __syncthreads();
    for (int off = 1; off < T; off <<= 1) {
        int v = (t >= off) ? part[t - off] : 0;
        __syncthreads();
        part[t] += v;
        __syncthreads();
    }
    int run = (t > 0) ? part[t - 1] : 0;
    for (int i = beg; i < end; ++i) {
        int c = row_ptr[i];
        row_ptr[i] = run;
        cursor[i] = run;
        run += c;
    }
    if (t == T - 1) row_ptr[N_NODES] = part[T - 1];
}

__global__ void scatter_kernel(const int* __restrict__ src, const int* __restrict__ dst,
                               int* __restrict__ cursor, int* __restrict__ edges) {
    int e = blockIdx.x * blockDim.x + threadIdx.x;
    if (e < N_EDGES) {
        int pos = atomicAdd(&cursor[dst[e]], 1);  // int atomic: native
        edges[pos] = src[e];                      // dst implied by CSR position
    }
}

// ---------------- fused GraphConv layer ----------------
// Phase A: wave w owns dst rows [8w, 8w+8): register accumulation (lane = dim),
//          plain LDS write per row. ZERO atomics (hip atomicAdd(float) = CAS loop!).
// Phase B: wave w computes dims [8w,8w+8) for all 64 nodes; weights wave-uniform.
__global__ __launch_bounds__(BLOCK) void layer_kernel(
    const float* __restrict__ hin, float* __restrict__ hout,
    const float* __restrict__ Wrel, const float* __restrict__ brel,
    const float* __restrict__ Wroot,
    const int* __restrict__ row_ptr, const int* __restrict__ edges) {
    __shared__ float agg_s[BN * SA];
    __shared__ float x_s[BN * SX];
    const int tid = threadIdx.x;
    const int lane = tid & 63;
    const int wave = __builtin_amdgcn_readfirstlane(tid >> 6);
    const int node0 = blockIdx.x * BN;
    const int nvalid = min(BN, N_NODES - node0);

    // stage own x rows (coalesced float4)
    for (int i = tid; i < nvalid * (DIM / 4); i += BLOCK) {
        int nl = i >> 4;
        int c = i & 15;
        float4 v = reinterpret_cast<const float4*>(hin)[(size_t)(node0 + nl) * (DIM / 4) + c];
        reinterpret_cast<float4*>(x_s)[nl * (SX / 4) + c] = v;
    }

    // Phase A: register accumulation over owned rows
    const int r0 = node0 + wave * RPW;
#pragma unroll
    for (int r8 = 0; r8 < RPW; ++r8) {
        int rg = r0 + r8;
        if (rg >= N_NODES) break;
        int e = row_ptr[rg];          // wave-uniform -> scalar
        const int ee = row_ptr[rg + 1];
        float acc = 0.f;
        for (; e + 4 <= ee; e += 4) {
            int s0 = edges[e + 0], s1 = edges[e + 1];
            int s2 = edges[e + 2], s3 = edges[e + 3];
            float v0 = hin[(size_t)s0 * DIM + lane];   // 4 independent 256B rows in flight
            float v1 = hin[(size_t)s1 * DIM + lane];
            float v2 = hin[(size_t)s2 * DIM + lane];
            float v3 = hin[(size_t)s3 * DIM + lane];
            acc += (v0 + v1) + (v2 + v3);
        }
        for (; e < ee; ++e) acc += hin[(size_t)edges[e] * DIM + lane];
        agg_s[(wave * RPW + r8) * SA + lane] = acc;    // plain write, wave owns row
    }
    __syncthreads();

    // Phase B: node = lane, dim-octet = wave
    const int d0 = wave * 8;
    float out[8];
#pragma unroll
    for (int j = 0; j < 8; ++j) out[j] = brel[d0 + j];  // uniform -> scalar
    const float* ar = &agg_s[lane * SA];
    const float* xr = &x_s[lane * SX];
    for (int k = 0; k < DIM; ++k) {
        float a = ar[k];
        float xv = xr[k];
        const float* wr = &Wrel[k * DIM + d0];   // wave-uniform -> s_load
        const float* wo = &Wroot[k * DIM + d0];
#pragma unroll
        for (int j = 0; j < 8; ++j)
            out[j] = fmaf(a, wr[j], fmaf(xv, wo[j], out[j]));
    }

    __syncthreads();  // all waves done reading x_s
    if (lane < nvalid) {
#pragma unroll
        for (int j = 0; j < 8; ++j) x_s[lane * SX + d0 + j] = fmaxf(out[j], 0.f);
    }
    __syncthreads();

    // coalesced float4 store
    for (int i = tid; i < nvalid * (DIM / 4); i += BLOCK) {
        int nl = i >> 4;
        int c = i & 15;
        float4 v = reinterpret_cast<const float4*>(x_s)[nl * (SX / 4) + c];
        reinterpret_cast<float4*>(hout)[(size_t)(node0 + nl) * (DIM / 4) + c] = v;
    }
}

// ---------------- global add pool ----------------
__global__ __launch_bounds__(256) void pool_kernel(const float* __restrict__ h,
                                                   const int* __restrict__ batch,
                                                   float* __restrict__ g) {
    int gtid = blockIdx.x * blockDim.x + threadIdx.x;
    int w = gtid >> 6;
    int lane = gtid & 63;
    const int NW = 1024;
    const int CH = (N_NODES + NW - 1) / NW;  // 98
    int nb = w * CH;
    int ne = min(nb + CH, N_NODES);
    if (nb >= ne) return;
    float acc = 0.f;
    int cur = batch[nb];
    for (int n = nb; n < ne; ++n) {
        int b = batch[n];  // wave-uniform broadcast
        if (b != cur) {
            atomicAdd(&g[(size_t)cur * DIM + lane], acc);
            acc = 0.f;
            cur = b;
        }
        acc += h[(size_t)n * DIM + lane];
    }
    atomicAdd(&g[(size_t)cur * DIM + lane], acc);
}

// ---------------- classifier head ----------------
__global__ __launch_bounds__(256) void head_kernel(
    const float* __restrict__ g, const float* __restrict__ W1, const float* __restrict__ b1,
    const float* __restrict__ W2, const float* __restrict__ b2, float* __restrict__ y) {
    int gid = blockIdx.x * blockDim.x + threadIdx.x;
    if (gid >= N_GRAPHS) return;
    float t[DIM];
#pragma unroll
    for (int d = 0; d < DIM; ++d) t[d] = b1[d];
    const float4* gp = reinterpret_cast<const float4*>(g + (size_t)gid * DIM);
    for (int kk = 0; kk < DIM / 4; ++kk) {
        float4 gv = gp[kk];
        float ga[4] = {gv.x, gv.y, gv.z, gv.w};
#pragma unroll
        for (int c = 0; c < 4; ++c) {
            int k = 4 * kk + c;
            float v = ga[c];
#pragma unroll
            for (int d = 0; d < DIM; ++d) t[d] = fmaf(v, W1[k * DIM + d], t[d]);
        }
    }
#pragma unroll
    for (int d = 0; d < DIM; ++d) t[d] = fmaxf(t[d], 0.f);
    for (int o = 0; o < OUT_DIM; ++o) {
        float acc = b2[o];
#pragma unroll
        for (int d = 0; d < DIM; ++d) acc = fmaf(t[d], W2[d * OUT_DIM + o], acc);
        y[(size_t)gid * OUT_DIM + o] = acc;
    }
}

extern "C" void kernel_launch(void* const* d_in, const int* in_sizes, int n_in,
                              void* d_out, int out_size, void* d_ws, size_t ws_size,
                              hipStream_t stream) {
    const float* x     = (const float*)d_in[0];
    const int*   eidx  = (const int*)d_in[1];
    const int*   batch = (const int*)d_in[2];
    const float* Wrel  = (const float*)d_in[3];
    const float* brel  = (const float*)d_in[4];
    const float* Wroot = (const float*)d_in[5];
    const float* W1    = (const float*)d_in[6];
    const float* b1    = (const float*)d_in[7];
    const float* W2    = (const float*)d_in[8];
    const float* b2    = (const float*)d_in[9];
    float* y = (float*)d_out;

    char* ws = (char*)d_ws;
    const size_t HBYTES = (size_t)N_NODES * DIM * sizeof(float);  // 25.6 MB
    size_t off = 0;
    float* hA = (float*)(ws + off); off += HBYTES;
    float* hB = (float*)(ws + off); off += HBYTES;
    int* row_ptr = (int*)(ws + off); off += (((size_t)(N_NODES + 1) * 4 + 255) / 256) * 256;
    int* cursor  = (int*)(ws + off); off += (((size_t)N_NODES * 4 + 255) / 256) * 256;
    int* edges   = (int*)(ws + off); off += (size_t)N_EDGES * 4;
    float* g = (float*)(ws + off); off += (size_t)N_GRAPHS * DIM * 4;

    const int* src = eidx;
    const int* dst = eidx + N_EDGES;

    // CSR build (once, reused across 4 layers)
    hipMemsetAsync(row_ptr, 0, (size_t)(N_NODES + 1) * sizeof(int), stream);
    count_kernel<<<(N_EDGES + 255) / 256, 256, 0, stream>>>(dst, row_ptr);
    scan_kernel<<<1, 1024, 0, stream>>>(row_ptr, cursor);
    scatter_kernel<<<(N_EDGES + 255) / 256, 256, 0, stream>>>(src, dst, cursor, edges);

    // 4 GraphConv layers, ping-pong
    const float* hin = x;
    float* bufs[2] = {hA, hB};
    for (int l = 0; l < NLAYERS; ++l) {
        float* hout = bufs[l & 1];
        layer_kernel<<<NB, BLOCK, 0, stream>>>(hin, hout,
                                               Wrel + (size_t)l * DIM * DIM,
                                               brel + (size_t)l * DIM,
                                               Wroot + (size_t)l * DIM * DIM,
                                               row_ptr, edges);
        hin = hout;
    }

    // global add pool
    hipMemsetAsync(g, 0, (size_t)N_GRAPHS * DIM * sizeof(float), stream);
    pool_kernel<<<256, 256, 0, stream>>>(hin, batch, g);

    // head
    head_kernel<<<(N_GRAPHS + 255) / 256, 256, 0, stream>>>(g, W1, b1, W2, b2, y);
}

// Round 6
// 561.876 us; speedup vs baseline: 4.5328x; 1.3806x over previous
//
#include <hip/hip_runtime.h>

#define N_NODES 100000
#define N_EDGES 1000000
#define DIM 64
#define N_GRAPHS 1024
#define OUT_DIM 16
#define NLAYERS 4

#define BN 64        // nodes per block in layer kernel
#define NB 1563      // ceil(N_NODES/BN)
#define BLOCK 512    // 8 waves
#define NWAVES 8
#define RPW 8        // dst rows owned per wave (BN/NWAVES) -> no atomics
#define SA 65        // agg_s row stride: 65%32==1 -> 2-way alias, free
#define SX 68        // x_s row stride: mult of 4 for float4 LDS ops

#define SCAN_NB 98   // ceil((N_NODES+1)/1024)

// ---------------- CSR build ----------------
__global__ void count_kernel(const int* __restrict__ dst, int* __restrict__ counts) {
    int e = blockIdx.x * blockDim.x + threadIdx.x;
    if (e < N_EDGES) atomicAdd(&counts[dst[e]], 1);  // int atomic: native
}

// coalesced 3-phase scan (old single-block chunked scan was 230us: each wave-load
// touched 64 distinct cachelines -> latency-serialized on one CU)
__global__ __launch_bounds__(1024) void scan_reduce_kernel(const int* __restrict__ counts,
                                                           int* __restrict__ bsums) {
    int i = blockIdx.x * 1024 + threadIdx.x;
    int v = (i < N_NODES) ? counts[i] : 0;
    __shared__ int ws_[16];
    for (int off = 32; off > 0; off >>= 1) v += __shfl_down(v, off, 64);
    if ((threadIdx.x & 63) == 0) ws_[threadIdx.x >> 6] = v;
    __syncthreads();
    if (threadIdx.x < 16) {
        int s = ws_[threadIdx.x];
        for (int off = 8; off > 0; off >>= 1) s += __shfl_down(s, off, 16);
        if (threadIdx.x == 0) bsums[blockIdx.x] = s;
    }
}

__global__ __launch_bounds__(128) void scan_sums_kernel(int* __restrict__ bsums) {
    __shared__ int t[128];
    int i = threadIdx.x;
    t[i] = (i < SCAN_NB) ? bsums[i] : 0;
    __syncthreads();
    for (int off = 1; off < 128; off <<= 1) {
        int v = (i >= off) ? t[i - off] : 0;
        __syncthreads();
        t[i] += v;
        __syncthreads();
    }
    if (i < SCAN_NB) bsums[i] = (i > 0) ? t[i - 1] : 0;  // exclusive
}

__global__ __launch_bounds__(1024) void scan_apply_kernel(const int* __restrict__ counts,
                                                          const int* __restrict__ bsums,
                                                          int* __restrict__ row_ptr,
                                                          int* __restrict__ cursor) {
    int i = blockIdx.x * 1024 + threadIdx.x;
    int v = (i < N_NODES) ? counts[i] : 0;
    int lane = threadIdx.x & 63, w = threadIdx.x >> 6;
    int inc = v;
    for (int off = 1; off < 64; off <<= 1) {
        int u = __shfl_up(inc, off, 64);
        if (lane >= off) inc += u;
    }
    __shared__ int wsum[16];
    if (lane == 63) wsum[w] = inc;
    __syncthreads();
    if (threadIdx.x < 16) {
        int s = wsum[threadIdx.x];
        for (int off = 1; off < 16; off <<= 1) {
            int u = __shfl_up(s, off, 16);
            if (threadIdx.x >= off) s += u;
        }
        wsum[threadIdx.x] = s;
    }
    __syncthreads();
    int excl = inc - v + (w > 0 ? wsum[w - 1] : 0) + bsums[blockIdx.x];
    if (i <= N_NODES) row_ptr[i] = excl;   // in-place over counts: each slot read
    if (i < N_NODES) cursor[i] = excl;     // only by the thread that overwrites it
}

__global__ void scatter_kernel(const int* __restrict__ src, const int* __restrict__ dst,
                               int* __restrict__ cursor, int* __restrict__ edges) {
    int e = blockIdx.x * blockDim.x + threadIdx.x;
    if (e < N_EDGES) {
        int pos = atomicAdd(&cursor[dst[e]], 1);  // int atomic: native
        edges[pos] = src[e];
    }
}

// ---------------- fused GraphConv layer ----------------
// Phase A: wave w owns dst rows [8w,8w+8). Quad-gather: 16 lanes per src row,
//          float4/lane -> 1KB/instruction, 4 edges/step. Cross-group shfl_xor
//          reduce, plain LDS writes. ZERO fp32 atomics (HIP atomicAdd(float)=CAS).
// Phase B: wave w computes dims [8w,8w+8) for all 64 nodes; weights wave-uniform.
__global__ __launch_bounds__(BLOCK) void layer_kernel(
    const float* __restrict__ hin, float* __restrict__ hout,
    const float* __restrict__ Wrel, const float* __restrict__ brel,
    const float* __restrict__ Wroot,
    const int* __restrict__ row_ptr, const int* __restrict__ edges) {
    __shared__ float agg_s[BN * SA];
    __shared__ float x_s[BN * SX];
    const int tid = threadIdx.x;
    const int lane = tid & 63;
    const int wave = __builtin_amdgcn_readfirstlane(tid >> 6);
    const int grp = lane >> 4;   // which of 4 concurrent edges
    const int gl = lane & 15;    // float4 slot within row
    const int node0 = blockIdx.x * BN;
    const int nvalid = min(BN, N_NODES - node0);

    // stage own x rows (coalesced float4)
    for (int i = tid; i < nvalid * (DIM / 4); i += BLOCK) {
        int nl = i >> 4;
        int c = i & 15;
        float4 v = reinterpret_cast<const float4*>(hin)[(size_t)(node0 + nl) * (DIM / 4) + c];
        reinterpret_cast<float4*>(x_s)[nl * (SX / 4) + c] = v;
    }

    // Phase A
    const float4* hin4 = reinterpret_cast<const float4*>(hin);
    const int r0 = node0 + wave * RPW;
#pragma unroll
    for (int r8 = 0; r8 < RPW; ++r8) {
        int rg = r0 + r8;
        if (rg >= N_NODES) break;
        int e = row_ptr[rg];            // wave-uniform -> scalar
        const int ee = row_ptr[rg + 1];
        float4 acc = make_float4(0.f, 0.f, 0.f, 0.f);
        for (; e + 8 <= ee; e += 8) {   // 8 edges (2KB) in flight
            int s0 = edges[e + grp];
            int s1 = edges[e + 4 + grp];
            float4 v0 = hin4[(size_t)s0 * (DIM / 4) + gl];
            float4 v1 = hin4[(size_t)s1 * (DIM / 4) + gl];
            acc.x += v0.x + v1.x; acc.y += v0.y + v1.y;
            acc.z += v0.z + v1.z; acc.w += v0.w + v1.w;
        }
        for (; e + 4 <= ee; e += 4) {
            int s = edges[e + grp];
            float4 v = hin4[(size_t)s * (DIM / 4) + gl];
            acc.x += v.x; acc.y += v.y; acc.z += v.z; acc.w += v.w;
        }
        int rem = ee - e;
        if (grp < rem) {
            int s = edges[e + grp];
            float4 v = hin4[(size_t)s * (DIM / 4) + gl];
            acc.x += v.x; acc.y += v.y; acc.z += v.z; acc.w += v.w;
        }
        // reduce across the 4 groups (lanes differing in bits 4,5)
        acc.x += __shfl_xor(acc.x, 16, 64); acc.y += __shfl_xor(acc.y, 16, 64);
        acc.z += __shfl_xor(acc.z, 16, 64); acc.w += __shfl_xor(acc.w, 16, 64);
        acc.x += __shfl_xor(acc.x, 32, 64); acc.y += __shfl_xor(acc.y, 32, 64);
        acc.z += __shfl_xor(acc.z, 32, 64); acc.w += __shfl_xor(acc.w, 32, 64);
        if (grp == 0) {  // 16 lanes, stride-4 banks -> 2-way alias, free
            float* base = &agg_s[(wave * RPW + r8) * SA + gl * 4];
            base[0] = acc.x; base[1] = acc.y; base[2] = acc.z; base[3] = acc.w;
        }
    }
    __syncthreads();

    // Phase B: node = lane, dim-octet = wave
    const int d0 = wave * 8;
    float out[8];
#pragma unroll
    for (int j = 0; j < 8; ++j) out[j] = brel[d0 + j];  // uniform -> scalar
    const float* ar = &agg_s[lane * SA];
    const float* xr = &x_s[lane * SX];
    for (int k = 0; k < DIM; ++k) {
        float a = ar[k];
        float xv = xr[k];
        const float* wr = &Wrel[k * DIM + d0];   // wave-uniform -> s_load
        const float* wo = &Wroot[k * DIM + d0];
#pragma unroll
        for (int j = 0; j < 8; ++j)
            out[j] = fmaf(a, wr[j], fmaf(xv, wo[j], out[j]));
    }

    __syncthreads();  // all waves done reading x_s
    if (lane < nvalid) {
#pragma unroll
        for (int j = 0; j < 8; ++j) x_s[lane * SX + d0 + j] = fmaxf(out[j], 0.f);
    }
    __syncthreads();

    for (int i = tid; i < nvalid * (DIM / 4); i += BLOCK) {
        int nl = i >> 4;
        int c = i & 15;
        float4 v = reinterpret_cast<const float4*>(x_s)[nl * (SX / 4) + c];
        reinterpret_cast<float4*>(hout)[(size_t)(node0 + nl) * (DIM / 4) + c] = v;
    }
}

// ---------------- global add pool ----------------
__global__ __launch_bounds__(256) void pool_kernel(const float* __restrict__ h,
                                                   const int* __restrict__ batch,
                                                   float* __restrict__ g) {
    int gtid = blockIdx.x * blockDim.x + threadIdx.x;
    int w = gtid >> 6;
    int lane = gtid & 63;
    const int NW = 1024;
    const int CH = (N_NODES + NW - 1) / NW;  // 98
    int nb = w * CH;
    int ne = min(nb + CH, N_NODES);
    if (nb >= ne) return;
    float acc = 0.f;
    int cur = batch[nb];
    for (int n = nb; n < ne; ++n) {
        int b = batch[n];  // wave-uniform broadcast
        if (b != cur) {
            atomicAdd(&g[(size_t)cur * DIM + lane], acc);
            acc = 0.f;
            cur = b;
        }
        acc += h[(size_t)n * DIM + lane];
    }
    atomicAdd(&g[(size_t)cur * DIM + lane], acc);
}

// ---------------- classifier head ----------------
__global__ __launch_bounds__(256) void head_kernel(
    const float* __restrict__ g, const float* __restrict__ W1, const float* __restrict__ b1,
    const float* __restrict__ W2, const float* __restrict__ b2, float* __restrict__ y) {
    int gid = blockIdx.x * blockDim.x + threadIdx.x;
    if (gid >= N_GRAPHS) return;
    float t[DIM];
#pragma unroll
    for (int d = 0; d < DIM; ++d) t[d] = b1[d];
    const float4* gp = reinterpret_cast<const float4*>(g + (size_t)gid * DIM);
    for (int kk = 0; kk < DIM / 4; ++kk) {
        float4 gv = gp[kk];
        float ga[4] = {gv.x, gv.y, gv.z, gv.w};
#pragma unroll
        for (int c = 0; c < 4; ++c) {
            int k = 4 * kk + c;
            float v = ga[c];
#pragma unroll
            for (int d = 0; d < DIM; ++d) t[d] = fmaf(v, W1[k * DIM + d], t[d]);
        }
    }
#pragma unroll
    for (int d = 0; d < DIM; ++d) t[d] = fmaxf(t[d], 0.f);
    for (int o = 0; o < OUT_DIM; ++o) {
        float acc = b2[o];
#pragma unroll
        for (int d = 0; d < DIM; ++d) acc = fmaf(t[d], W2[d * OUT_DIM + o], acc);
        y[(size_t)gid * OUT_DIM + o] = acc;
    }
}

extern "C" void kernel_launch(void* const* d_in, const int* in_sizes, int n_in,
                              void* d_out, int out_size, void* d_ws, size_t ws_size,
                              hipStream_t stream) {
    const float* x     = (const float*)d_in[0];
    const int*   eidx  = (const int*)d_in[1];
    const int*   batch = (const int*)d_in[2];
    const float* Wrel  = (const float*)d_in[3];
    const float* brel  = (const float*)d_in[4];
    const float* Wroot = (const float*)d_in[5];
    const float* W1    = (const float*)d_in[6];
    const float* b1    = (const float*)d_in[7];
    const float* W2    = (const float*)d_in[8];
    const float* b2    = (const float*)d_in[9];
    float* y = (float*)d_out;

    char* ws = (char*)d_ws;
    const size_t HBYTES = (size_t)N_NODES * DIM * sizeof(float);  // 25.6 MB
    size_t off = 0;
    float* hA = (float*)(ws + off); off += HBYTES;
    float* hB = (float*)(ws + off); off += HBYTES;
    int* row_ptr = (int*)(ws + off); off += (((size_t)(N_NODES + 1) * 4 + 255) / 256) * 256;
    int* cursor  = (int*)(ws + off); off += (((size_t)N_NODES * 4 + 255) / 256) * 256;
    int* edges   = (int*)(ws + off); off += (size_t)N_EDGES * 4;
    float* g     = (float*)(ws + off); off += (size_t)N_GRAPHS * DIM * 4;
    int* bsums   = (int*)(ws + off); off += 128 * 4;

    const int* src = eidx;
    const int* dst = eidx + N_EDGES;

    // CSR build (once, reused across 4 layers)
    hipMemsetAsync(row_ptr, 0, (size_t)N_NODES * sizeof(int), stream);
    count_kernel<<<(N_EDGES + 255) / 256, 256, 0, stream>>>(dst, row_ptr);
    scan_reduce_kernel<<<SCAN_NB, 1024, 0, stream>>>(row_ptr, bsums);
    scan_sums_kernel<<<1, 128, 0, stream>>>(bsums);
    scan_apply_kernel<<<SCAN_NB, 1024, 0, stream>>>(row_ptr, bsums, row_ptr, cursor);
    scatter_kernel<<<(N_EDGES + 255) / 256, 256, 0, stream>>>(src, dst, cursor, edges);

    // 4 GraphConv layers, ping-pong
    const float* hin = x;
    float* bufs[2] = {hA, hB};
    for (int l = 0; l < NLAYERS; ++l) {
        float* hout = bufs[l & 1];
        layer_kernel<<<NB, BLOCK, 0, stream>>>(hin, hout,
                                               Wrel + (size_t)l * DIM * DIM,
                                               brel + (size_t)l * DIM,
                                               Wroot + (size_t)l * DIM * DIM,
                                               row_ptr, edges);
        hin = hout;
    }

    // global add pool
    hipMemsetAsync(g, 0, (size_t)N_GRAPHS * DIM * sizeof(float), stream);
    pool_kernel<<<256, 256, 0, stream>>>(hin, batch, g);

    // head
    head_kernel<<<(N_GRAPHS + 255) / 256, 256, 0, stream>>>(g, W1, b1, W2, b2, y);
}